// Round 9
// baseline (276.463 us; speedup 1.0000x reference)
//
#include <hip/hip_runtime.h>
#include <stdint.h>

typedef __bf16 bf16x8 __attribute__((ext_vector_type(8)));
typedef float  f32x4  __attribute__((ext_vector_type(4)));
typedef float  float4v __attribute__((ext_vector_type(4)));
typedef short  short8 __attribute__((ext_vector_type(8)));
typedef short  short4v __attribute__((ext_vector_type(4)));

static constexpr int Mtot = 8192;        // B*S
static constexpr int Ntot = 2048;        // D_OUT
static constexpr int Ktot = 2048;        // D_IN
static constexpr int NE = 8, NR = 16;
static constexpr int R2 = NE * NR;       // 128 stacked rank
static constexpr float SCALING = 16.0f / 16.0f;

template<int V> struct IC { static constexpr int val = V; };

__device__ __forceinline__ ushort f2bf(float f) {
  union { float f; uint32_t u; } v; v.f = f;
  uint32_t r = (v.u + 0x7FFFu + ((v.u >> 16) & 1u)) >> 16;
  return (ushort)r;
}

__device__ __forceinline__ void lds16(const void* g, void* l) {
  __builtin_amdgcn_global_load_lds(
      (const __attribute__((address_space(1))) void*)g,
      (__attribute__((address_space(3))) void*)l, 16, 0, 0);
}

// ---------- kernel 1: cvt x -> bf16 (dense) + build Abt/Bst bf16 ----------
__global__ __launch_bounds__(256) void k_prep(const float* __restrict__ x,
                                              ushort* __restrict__ xb,
                                              const float* __restrict__ lA,   // [E][R][K] = [128][2048]
                                              const float* __restrict__ lB,   // [E][N][R]
                                              const int* __restrict__ mask,   // [E]
                                              ushort* __restrict__ Abt,       // [2048][128]
                                              ushort* __restrict__ Bst) {     // [2048][128]
  int tid = threadIdx.x;
  if (blockIdx.x < 8192) {
    size_t base = (size_t)blockIdx.x * 2048;
    int t4 = tid * 4;
    float4v a = *reinterpret_cast<const float4v*>(x + base + t4);
    float4v c = *reinterpret_cast<const float4v*>(x + base + 1024 + t4);
    short4v s0, s1;
    s0[0] = (short)f2bf(a[0]); s0[1] = (short)f2bf(a[1]);
    s0[2] = (short)f2bf(a[2]); s0[3] = (short)f2bf(a[3]);
    s1[0] = (short)f2bf(c[0]); s1[1] = (short)f2bf(c[1]);
    s1[2] = (short)f2bf(c[2]); s1[3] = (short)f2bf(c[3]);
    *reinterpret_cast<short4v*>(xb + base + t4) = s0;
    *reinterpret_cast<short4v*>(xb + base + 1024 + t4) = s1;
  } else if (blockIdx.x < 8200) {
    int d = (blockIdx.x - 8192) * 256 + tid;
    short8 buf[16];
    #pragma unroll 8
    for (int i = 0; i < R2; ++i)
      ((short*)buf)[i] = (short)f2bf(lA[(size_t)i * Ktot + d]);
    #pragma unroll
    for (int q = 0; q < 16; ++q)
      *reinterpret_cast<short8*>(Abt + (size_t)d * R2 + q * 8) = buf[q];
  } else {
    int o = (blockIdx.x - 8200) * 256 + tid;
    short8 buf[16];
    #pragma unroll
    for (int e = 0; e < NE; ++e) {
      float m = (mask[e] != 0) ? SCALING : 0.0f;
      #pragma unroll
      for (int rg = 0; rg < 4; ++rg) {
        float4v v = *reinterpret_cast<const float4v*>(lB + ((size_t)e * Ntot + o) * NR + rg * 4);
        ((short*)buf)[e * 16 + rg * 4 + 0] = (short)f2bf(v[0] * m);
        ((short*)buf)[e * 16 + rg * 4 + 1] = (short)f2bf(v[1] * m);
        ((short*)buf)[e * 16 + rg * 4 + 2] = (short)f2bf(v[2] * m);
        ((short*)buf)[e * 16 + rg * 4 + 3] = (short)f2bf(v[3] * m);
      }
    }
    #pragma unroll
    for (int q = 0; q < 16; ++q)
      *reinterpret_cast<short8*>(Bst + (size_t)o * R2 + q * 8) = buf[q];
  }
}

// ---------- kernel 2: W_eff via MFMA: Wb = bf16(W + Bst @ Abt^T) ----------
__global__ __launch_bounds__(256) void k_weff_mfma(const ushort* __restrict__ Bst, // [2048][128]
                                                   const ushort* __restrict__ Abt, // [2048][128]
                                                   const float* __restrict__ W,    // [2048][2048]
                                                   ushort* __restrict__ Wb) {      // [2048][2048]
  __shared__ __align__(128) char sA[32768];  // Bst tile: 128 rows(o) x 256B
  __shared__ __align__(128) char sB[32768];  // Abt tile: 128 rows(d) x 256B
  int bid = blockIdx.x;
  int o0 = (bid >> 4) * 128;
  int d0 = (bid & 15) * 128;
  int tid = threadIdx.x, w = tid >> 6, l = tid & 63;

  int srow = w * 32 + (l >> 4);
  int scolb = (l & 15) * 16;
  #pragma unroll
  for (int j = 0; j < 8; ++j) {
    int row = srow + j * 4;
    int colb = scolb ^ ((row & 7) << 4);
    lds16((const char*)Bst + (size_t)(o0 + row) * 256 + colb, sA + w * 8192 + j * 1024);
    lds16((const char*)Abt + (size_t)(d0 + row) * 256 + colb, sB + w * 8192 + j * 1024);
  }
  __syncthreads();

  int wr = w >> 1, wc = w & 1;     // wave -> 64x64 out sub-tile
  int fr = l & 15;
  int fk16 = (l >> 4) * 16;
  int xm = (fr & 7) << 4;

  f32x4 acc[4][4];
  #pragma unroll
  for (int i = 0; i < 4; ++i)
    #pragma unroll
    for (int j = 0; j < 4; ++j) acc[i][j] = f32x4{0.f, 0.f, 0.f, 0.f};

  #pragma unroll
  for (int ks = 0; ks < 4; ++ks) {
    int kx = (ks * 64 + fk16) ^ xm;
    bf16x8 aF[4], bF[4];
    #pragma unroll
    for (int mi = 0; mi < 4; ++mi)
      aF[mi] = *reinterpret_cast<const bf16x8*>(sA + (wr * 64 + mi * 16 + fr) * 256 + kx);
    #pragma unroll
    for (int nj = 0; nj < 4; ++nj)
      bF[nj] = *reinterpret_cast<const bf16x8*>(sB + (wc * 64 + nj * 16 + fr) * 256 + kx);
    #pragma unroll
    for (int mi = 0; mi < 4; ++mi)
      #pragma unroll
      for (int nj = 0; nj < 4; ++nj)
        acc[mi][nj] = __builtin_amdgcn_mfma_f32_16x16x32_bf16(aF[mi], bF[nj], acc[mi][nj], 0, 0, 0);
  }

  int rr4 = (l >> 4) * 4;
  #pragma unroll
  for (int nj = 0; nj < 4; ++nj) {
    int col = d0 + wc * 64 + nj * 16 + fr;
    #pragma unroll
    for (int mi = 0; mi < 4; ++mi) {
      int row0 = o0 + wr * 64 + mi * 16 + rr4;
      #pragma unroll
      for (int r = 0; r < 4; ++r) {
        float v = acc[mi][nj][r] + W[(size_t)(row0 + r) * Ktot + col];
        Wb[(size_t)(row0 + r) * Ktot + col] = f2bf(v);
      }
    }
  }
}

// ---------- kernel 3a (A/B variant): 256x256, BK=64, 4-phase-per-K-tile ----------
// Template-family structure: per phase {ds_read subtile; stage; barrier;
// lgkmcnt(0); setprio(1); 16 MFMA; setprio(0); barrier}. 2 LDS buffers.
// Stages of tile t+1 issued in phases 0-1 of tile t; cheap vmcnt(0)+barrier
// at the tile seam (issue-to-wait distance ~2 phases >> HBM latency).
__global__ __launch_bounds__(512, 2) void k_gemm256_v2(const ushort* __restrict__ Xb,
                                                       const ushort* __restrict__ Wb,
                                                       const float* __restrict__ bias,
                                                       float* __restrict__ out) {
  constexpr int NT2 = Ktot / 64;          // 32 K-tiles
  constexpr int NTN = Ntot / 256;         // 8
  __shared__ __align__(128) char smem2[2 * 65536];  // per buf: A 32KB | B 32KB

  int nwg = gridDim.x;
  int orig = blockIdx.x;
  int wg = (orig & 7) * (nwg >> 3) + (orig >> 3);
  int mBase = (wg / NTN) * 256;
  int nBase = (wg % NTN) * 256;

  int tid = threadIdx.x;
  int w = tid >> 6, l = tid & 63;
  int wr = w >> 2, wc = w & 3;            // wave -> 128x64 output sub-tile

  // staging: G-load g covers 64 rows x 128B; thread: row=tid>>3, col=(tid&7)*16.
  int sRow = tid >> 3;
  int sColbX = ((tid & 7) * 16) ^ ((sRow & 7) << 4);   // pre-swizzled source col
  const char* xbB = (const char*)Xb;
  const char* wbB = (const char*)Wb;
  const char* srcA2 = xbB + (size_t)(mBase + sRow) * 4096 + sColbX;
  const char* srcB2 = wbB + (size_t)(nBase + sRow) * 4096 + sColbX;

  // read addressing: LDS[row][c], c = (KK*64 + (l>>4)*16) ^ ((row&7)<<4), row&7==fr&7
  int fr = l & 15;
  int xm = (fr & 7) << 4;
  int colx0 = ((l >> 4) * 16) ^ xm;
  int colx1 = (64 + ((l >> 4) * 16)) ^ xm;
  int aRdBase = (wr * 128 + fr) * 128;           // + MH*8192 + mi*2048 + colx
  int bRdBase = 32768 + (wc * 64 + fr) * 128;    // + nj*2048 + colx

  f32x4 acc[8][4];
  #pragma unroll
  for (int i = 0; i < 8; ++i)
    #pragma unroll
    for (int j = 0; j < 4; ++j) acc[i][j] = f32x4{0.f, 0.f, 0.f, 0.f};

  bf16x8 aF[4], bF[4];

  // prologue: stage tile 0 fully, drain, sync.
  #pragma unroll
  for (int g = 0; g < 4; ++g)
    lds16(srcA2 + (size_t)g * 262144, smem2 + g * 8192 + w * 1024);
  #pragma unroll
  for (int g = 0; g < 4; ++g)
    lds16(srcB2 + (size_t)g * 262144, smem2 + 32768 + g * 8192 + w * 1024);
  asm volatile("s_waitcnt vmcnt(0)" ::: "memory");
  __syncthreads();

  auto phase = [&](auto MHc, auto KKc, auto TAILc, int stageSel, bool pref,
                   const char* bufR, char* bufW, int tn) {
    constexpr int MH = decltype(MHc)::val;
    constexpr int KK = decltype(KKc)::val;
    constexpr int TAIL = decltype(TAILc)::val;
    const int cx = (KK == 0) ? colx0 : colx1;
    if (MH == 0) {
      #pragma unroll
      for (int nj = 0; nj < 4; ++nj)
        bF[nj] = *reinterpret_cast<const bf16x8*>(bufR + bRdBase + nj * 2048 + cx);
    }
    #pragma unroll
    for (int mi = 0; mi < 4; ++mi)
      aF[mi] = *reinterpret_cast<const bf16x8*>(bufR + aRdBase + MH * 8192 + mi * 2048 + cx);
    if (pref && stageSel == 0) {
      #pragma unroll
      for (int g = 0; g < 4; ++g)
        lds16(srcA2 + (size_t)g * 262144 + (size_t)tn * 128, bufW + g * 8192 + w * 1024);
    } else if (pref && stageSel == 1) {
      #pragma unroll
      for (int g = 0; g < 4; ++g)
        lds16(srcB2 + (size_t)g * 262144 + (size_t)tn * 128, bufW + 32768 + g * 8192 + w * 1024);
    }
    __builtin_amdgcn_s_barrier();
    asm volatile("s_waitcnt lgkmcnt(0)" ::: "memory");
    __builtin_amdgcn_sched_barrier(0);
    __builtin_amdgcn_s_setprio(1);
    #pragma unroll
    for (int mi = 0; mi < 4; ++mi)
      #pragma unroll
      for (int nj = 0; nj < 4; ++nj)
        acc[MH * 4 + mi][nj] =
            __builtin_amdgcn_mfma_f32_16x16x32_bf16(aF[mi], bF[nj], acc[MH * 4 + mi][nj], 0, 0, 0);
    __builtin_amdgcn_s_setprio(0);
    if (TAIL) asm volatile("s_waitcnt vmcnt(0)" ::: "memory");
    __builtin_amdgcn_s_barrier();
  };

  for (int t = 0; t < NT2; ++t) {
    const char* bufR = smem2 + (t & 1) * 65536;
    char* bufW = smem2 + ((t + 1) & 1) * 65536;
    bool pref = (t + 1 < NT2);
    phase(IC<0>{}, IC<0>{}, IC<0>{}, 0, pref, bufR, bufW, t + 1);
    phase(IC<1>{}, IC<0>{}, IC<0>{}, 1, pref, bufR, bufW, t + 1);
    phase(IC<0>{}, IC<1>{}, IC<0>{}, -1, false, bufR, bufW, t + 1);
    phase(IC<1>{}, IC<1>{}, IC<1>{}, -1, false, bufR, bufW, t + 1);
  }

  int rr = (l >> 4) * 4;
  #pragma unroll
  for (int mh = 0; mh < 2; ++mh)
    #pragma unroll
    for (int mi = 0; mi < 4; ++mi) {
      int row0 = mBase + wr * 128 + mh * 64 + mi * 16 + rr;
      #pragma unroll
      for (int nj = 0; nj < 4; ++nj) {
        int col = nBase + wc * 64 + nj * 16 + fr;
        float bb = bias[col];
        #pragma unroll
        for (int r = 0; r < 4; ++r)
          out[(size_t)(row0 + r) * Ntot + col] = acc[mh * 4 + mi][nj][r] + bb;
      }
    }
}

// ---------- kernel 3b: R8 depth-2 pipeline (unchanged, authoritative) ----------
__global__ __launch_bounds__(512, 2) void k_gemm256(const ushort* __restrict__ Xb,
                                                    const ushort* __restrict__ Wb,
                                                    const float* __restrict__ bias,
                                                    float* __restrict__ out) {
  constexpr int BK = 32;
  constexpr int NT = Ktot / BK;           // 64
  constexpr int NTN = Ntot / 256;         // 8
  __shared__ __align__(128) char smem[4 * 32768];   // ring: 4 x (A 16KB + B 16KB)

  int nwg = gridDim.x;                    // 256, %8==0
  int orig = blockIdx.x;
  int wg = (orig & 7) * (nwg >> 3) + (orig >> 3);
  int mBase = (wg / NTN) * 256;
  int nBase = (wg % NTN) * 256;

  int tid = threadIdx.x;
  int w = tid >> 6, l = tid & 63;
  int wr = w >> 2, wc = w & 3;            // wave -> 128x64 output sub-tile

  int rowOff = tid >> 2;
  int cbS = ((tid & 3) * 16) ^ (((tid >> 3) & 3) << 4);
  const char* xbB = (const char*)Xb;
  const char* wbB = (const char*)Wb;
  const char* src[4];
  src[0] = xbB + (size_t)(mBase +       rowOff) * (Ktot * 2) + cbS;  // A rows 0-127
  src[1] = xbB + (size_t)(mBase + 128 + rowOff) * (Ktot * 2) + cbS;  // A rows 128-255
  src[2] = wbB + (size_t)(nBase +       rowOff) * (Ktot * 2) + cbS;  // B rows 0-127
  src[3] = wbB + (size_t)(nBase + 128 + rowOff) * (Ktot * 2) + cbS;  // B rows 128-255
  int waveB = w * 1024;

  auto stage = [&](int bufn, int which, int tt) {
    lds16(src[which] + (size_t)tt * 64, smem + bufn * 32768 + which * 8192 + waveB);
  };

  int fr = l & 15;
  int fkb = (l >> 4) * 16;
  int kx = fkb ^ (((fr >> 1) & 3) << 4);
  int aRd = (wr * 128 + fr) * 64 + kx;            // + mi*1024
  int bRd = 16384 + (wc * 64 + fr) * 64 + kx;     // + nj*1024

  f32x4 acc[8][4];
  #pragma unroll
  for (int i = 0; i < 8; ++i)
    #pragma unroll
    for (int j = 0; j < 4; ++j) acc[i][j] = f32x4{0.f, 0.f, 0.f, 0.f};

  bf16x8 aLo[4], aHi[4], bX[4], bY[4];

  #pragma unroll
  for (int q = 0; q < 4; ++q) stage(0, q, 0);
  #pragma unroll
  for (int q = 0; q < 4; ++q) stage(1, q, 1);
  asm volatile("s_waitcnt vmcnt(4)" ::: "memory");
  __syncthreads();
  #pragma unroll
  for (int nj = 0; nj < 4; ++nj)
    bX[nj] = *reinterpret_cast<const bf16x8*>(smem + bRd + nj * 1024);
  #pragma unroll
  for (int mi = 0; mi < 4; ++mi)
    aLo[mi] = *reinterpret_cast<const bf16x8*>(smem + aRd + mi * 1024);

  auto tile_body = [&](int t, bf16x8 (&bCur)[4], bf16x8 (&bNxt)[4]) {
    const char* buf  = smem + (t & 3) * 32768;
    const char* bufN = smem + ((t + 1) & 3) * 32768;
    const bool pref = (t + 2 < NT);
    const int bn = (t + 2) & 3;

    if (pref) { stage(bn, 0, t + 2); stage(bn, 1, t + 2); }
    #pragma unroll
    for (int mi = 0; mi < 4; ++mi)
      aHi[mi] = *reinterpret_cast<const bf16x8*>(buf + aRd + (4 + mi) * 1024);
    __builtin_amdgcn_s_setprio(1);
    #pragma unroll
    for (int mi = 0; mi < 4; ++mi)
      #pragma unroll
      for (int nj = 0; nj < 4; ++nj)
        acc[mi][nj] = __builtin_amdgcn_mfma_f32_16x16x32_bf16(aLo[mi], bCur[nj], acc[mi][nj], 0, 0, 0);
    __builtin_amdgcn_s_setprio(0);

    if (pref) asm volatile("s_waitcnt vmcnt(2)" ::: "memory");
    else      asm volatile("s_waitcnt vmcnt(0)" ::: "memory");
    __builtin_amdgcn_s_barrier();
    if (pref) { stage(bn, 2, t + 2); stage(bn, 3, t + 2); }

    if (t + 1 < NT) {
      #pragma unroll
      for (int nj = 0; nj < 4; ++nj)
        bNxt[nj] = *reinterpret_cast<const bf16x8*>(bufN + bRd + nj * 1024);
      #pragma unroll
      for (int mi = 0; mi < 4; ++mi)
        aLo[mi] = *reinterpret_cast<const bf16x8*>(bufN + aRd + mi * 1024);
    }
    __builtin_amdgcn_s_setprio(1);
    #pragma unroll
    for (int mi = 0; mi < 4; ++mi)
      #pragma unroll
      for (int nj = 0; nj < 4; ++nj)
        acc[4 + mi][nj] = __builtin_amdgcn_mfma_f32_16x16x32_bf16(aHi[mi], bCur[nj], acc[4 + mi][nj], 0, 0, 0);
    __builtin_amdgcn_s_setprio(0);
  };

  for (int t = 0; t < NT; t += 2) {
    tile_body(t,     bX, bY);
    tile_body(t + 1, bY, bX);
  }

  int rr = (l >> 4) * 4;
  #pragma unroll
  for (int nj = 0; nj < 4; ++nj) {
    int col = nBase + wc * 64 + nj * 16 + fr;
    float bb = bias[col];
    #pragma unroll
    for (int mi = 0; mi < 8; ++mi) {
      int row0 = mBase + wr * 128 + mi * 16 + rr;
      #pragma unroll
      for (int r = 0; r < 4; ++r)
        out[(size_t)(row0 + r) * Ntot + col] = acc[mi][nj][r] + bb;
    }
  }
}

extern "C" void kernel_launch(void* const* d_in, const int* in_sizes, int n_in,
                              void* d_out, int out_size, void* d_ws, size_t ws_size,
                              hipStream_t stream) {
  const float* x    = (const float*)d_in[0];
  const float* W    = (const float*)d_in[1];
  const float* bias = (const float*)d_in[2];
  const float* lA   = (const float*)d_in[3];
  const float* lB   = (const float*)d_in[4];
  const int*   mask = (const int*)d_in[5];
  float* out = (float*)d_out;

  ushort* xb  = (ushort*)d_ws;                      // [M][K]   bf16: 33.55 MB
  ushort* wb  = xb + (size_t)Mtot * Ktot;           // [N][K]   bf16:  8.39 MB
  ushort* abt = wb + (size_t)Ntot * Ktot;           // [K][128] bf16:  0.52 MB
  ushort* bst = abt + (size_t)Ktot * R2;            // [N][128] bf16:  0.52 MB

  k_prep<<<8192 + 8 + 8, 256, 0, stream>>>(x, xb, lA, lB, mask, abt, bst);
  k_weff_mfma<<<(Ntot / 128) * (Ktot / 128), 256, 0, stream>>>(bst, abt, W, wb);
  // A/B: v2 (experimental 4-phase BK=64) first, v1 (validated) last = authoritative.
  k_gemm256_v2<<<(Mtot / 256) * (Ntot / 256), 512, 0, stream>>>(xb, wb, bias, out);
  k_gemm256<<<(Mtot / 256) * (Ntot / 256), 512, 0, stream>>>(xb, wb, bias, out);
}

// Round 10
// 219.675 us; speedup vs baseline: 1.2585x; 1.2585x over previous
//
#include <hip/hip_runtime.h>
#include <stdint.h>

typedef __bf16 bf16x8 __attribute__((ext_vector_type(8)));
typedef float  f32x4  __attribute__((ext_vector_type(4)));
typedef float  f32x16 __attribute__((ext_vector_type(16)));
typedef float  float4v __attribute__((ext_vector_type(4)));
typedef short  short8 __attribute__((ext_vector_type(8)));
typedef short  short4v __attribute__((ext_vector_type(4)));

static constexpr int Mtot = 8192;        // B*S
static constexpr int Ntot = 2048;        // D_OUT
static constexpr int Ktot = 2048;        // D_IN
static constexpr int NE = 8, NR = 16;
static constexpr int R2 = NE * NR;       // 128 stacked rank
static constexpr float SCALING = 16.0f / 16.0f;

__device__ __forceinline__ ushort f2bf(float f) {
  union { float f; uint32_t u; } v; v.f = f;
  uint32_t r = (v.u + 0x7FFFu + ((v.u >> 16) & 1u)) >> 16;
  return (ushort)r;
}

__device__ __forceinline__ void lds16(const void* g, void* l) {
  __builtin_amdgcn_global_load_lds(
      (const __attribute__((address_space(1))) void*)g,
      (__attribute__((address_space(3))) void*)l, 16, 0, 0);
}

// ---------- kernel 1: cvt x -> bf16 (dense) + build Abt/Bst bf16 ----------
__global__ __launch_bounds__(256) void k_prep(const float* __restrict__ x,
                                              ushort* __restrict__ xb,
                                              const float* __restrict__ lA,   // [E][R][K] = [128][2048]
                                              const float* __restrict__ lB,   // [E][N][R]
                                              const int* __restrict__ mask,   // [E]
                                              ushort* __restrict__ Abt,       // [2048][128]
                                              ushort* __restrict__ Bst) {     // [2048][128]
  int tid = threadIdx.x;
  if (blockIdx.x < 8192) {
    size_t base = (size_t)blockIdx.x * 2048;
    int t4 = tid * 4;
    float4v a = *reinterpret_cast<const float4v*>(x + base + t4);
    float4v c = *reinterpret_cast<const float4v*>(x + base + 1024 + t4);
    short4v s0, s1;
    s0[0] = (short)f2bf(a[0]); s0[1] = (short)f2bf(a[1]);
    s0[2] = (short)f2bf(a[2]); s0[3] = (short)f2bf(a[3]);
    s1[0] = (short)f2bf(c[0]); s1[1] = (short)f2bf(c[1]);
    s1[2] = (short)f2bf(c[2]); s1[3] = (short)f2bf(c[3]);
    *reinterpret_cast<short4v*>(xb + base + t4) = s0;
    *reinterpret_cast<short4v*>(xb + base + 1024 + t4) = s1;
  } else if (blockIdx.x < 8200) {
    int d = (blockIdx.x - 8192) * 256 + tid;
    short8 buf[16];
    #pragma unroll 8
    for (int i = 0; i < R2; ++i)
      ((short*)buf)[i] = (short)f2bf(lA[(size_t)i * Ktot + d]);
    #pragma unroll
    for (int q = 0; q < 16; ++q)
      *reinterpret_cast<short8*>(Abt + (size_t)d * R2 + q * 8) = buf[q];
  } else {
    int o = (blockIdx.x - 8200) * 256 + tid;
    short8 buf[16];
    #pragma unroll
    for (int e = 0; e < NE; ++e) {
      float m = (mask[e] != 0) ? SCALING : 0.0f;
      #pragma unroll
      for (int rg = 0; rg < 4; ++rg) {
        float4v v = *reinterpret_cast<const float4v*>(lB + ((size_t)e * Ntot + o) * NR + rg * 4);
        ((short*)buf)[e * 16 + rg * 4 + 0] = (short)f2bf(v[0] * m);
        ((short*)buf)[e * 16 + rg * 4 + 1] = (short)f2bf(v[1] * m);
        ((short*)buf)[e * 16 + rg * 4 + 2] = (short)f2bf(v[2] * m);
        ((short*)buf)[e * 16 + rg * 4 + 3] = (short)f2bf(v[3] * m);
      }
    }
    #pragma unroll
    for (int q = 0; q < 16; ++q)
      *reinterpret_cast<short8*>(Bst + (size_t)o * R2 + q * 8) = buf[q];
  }
}

// ---------- kernel 2: W_eff via MFMA: Wb = bf16(W + Bst @ Abt^T) ----------
__global__ __launch_bounds__(256) void k_weff_mfma(const ushort* __restrict__ Bst, // [2048][128]
                                                   const ushort* __restrict__ Abt, // [2048][128]
                                                   const float* __restrict__ W,    // [2048][2048]
                                                   ushort* __restrict__ Wb) {      // [2048][2048]
  __shared__ __align__(128) char sA[32768];  // Bst tile: 128 rows(o) x 256B
  __shared__ __align__(128) char sB[32768];  // Abt tile: 128 rows(d) x 256B
  int bid = blockIdx.x;
  int o0 = (bid >> 4) * 128;
  int d0 = (bid & 15) * 128;
  int tid = threadIdx.x, w = tid >> 6, l = tid & 63;

  int srow = w * 32 + (l >> 4);
  int scolb = (l & 15) * 16;
  #pragma unroll
  for (int j = 0; j < 8; ++j) {
    int row = srow + j * 4;
    int colb = scolb ^ ((row & 7) << 4);
    lds16((const char*)Bst + (size_t)(o0 + row) * 256 + colb, sA + w * 8192 + j * 1024);
    lds16((const char*)Abt + (size_t)(d0 + row) * 256 + colb, sB + w * 8192 + j * 1024);
  }
  __syncthreads();

  int wr = w >> 1, wc = w & 1;     // wave -> 64x64 out sub-tile
  int fr = l & 15;
  int fk16 = (l >> 4) * 16;
  int xm = (fr & 7) << 4;

  f32x4 acc[4][4];
  #pragma unroll
  for (int i = 0; i < 4; ++i)
    #pragma unroll
    for (int j = 0; j < 4; ++j) acc[i][j] = f32x4{0.f, 0.f, 0.f, 0.f};

  #pragma unroll
  for (int ks = 0; ks < 4; ++ks) {
    int kx = (ks * 64 + fk16) ^ xm;
    bf16x8 aF[4], bF[4];
    #pragma unroll
    for (int mi = 0; mi < 4; ++mi)
      aF[mi] = *reinterpret_cast<const bf16x8*>(sA + (wr * 64 + mi * 16 + fr) * 256 + kx);
    #pragma unroll
    for (int nj = 0; nj < 4; ++nj)
      bF[nj] = *reinterpret_cast<const bf16x8*>(sB + (wc * 64 + nj * 16 + fr) * 256 + kx);
    #pragma unroll
    for (int mi = 0; mi < 4; ++mi)
      #pragma unroll
      for (int nj = 0; nj < 4; ++nj)
        acc[mi][nj] = __builtin_amdgcn_mfma_f32_16x16x32_bf16(aF[mi], bF[nj], acc[mi][nj], 0, 0, 0);
  }

  int rr4 = (l >> 4) * 4;
  #pragma unroll
  for (int nj = 0; nj < 4; ++nj) {
    int col = d0 + wc * 64 + nj * 16 + fr;
    #pragma unroll
    for (int mi = 0; mi < 4; ++mi) {
      int row0 = o0 + wr * 64 + mi * 16 + rr4;
      #pragma unroll
      for (int r = 0; r < 4; ++r) {
        float v = acc[mi][nj][r] + W[(size_t)(row0 + r) * Ktot + col];
        Wb[(size_t)(row0 + r) * Ktot + col] = f2bf(v);
      }
    }
  }
}

// ---------- kernel 3: 256x256-tile 8-wave GEMM, 32x32x16 MFMA ----------
// R8's validated skeleton (ring-4, distance-2, counted vmcnt(2), XOR swizzle)
// with the MFMA shape switched 16x16x32 -> 32x32x16: higher pipe ceiling
// (2495 vs 2075 TF ubench), half the MFMA + frag-read instruction count.
// A/B frag: row=lane&31, k=(lane>>5)*8+j. C/D: col=lane&31,
// row=(reg&3)+8*(reg>>2)+4*(lane>>5).
__global__ __launch_bounds__(512, 2) void k_gemm256(const ushort* __restrict__ Xb,
                                                    const ushort* __restrict__ Wb,
                                                    const float* __restrict__ bias,
                                                    float* __restrict__ out) {
  constexpr int BK = 32;
  constexpr int NT = Ktot / BK;           // 64
  constexpr int NTN = Ntot / 256;         // 8
  __shared__ __align__(128) char smem[4 * 32768];   // ring: 4 x (A 16KB + B 16KB)

  int nwg = gridDim.x;                    // 256, %8==0
  int orig = blockIdx.x;
  int wg = (orig & 7) * (nwg >> 3) + (orig >> 3);
  int mBase = (wg / NTN) * 256;
  int nBase = (wg % NTN) * 256;

  int tid = threadIdx.x;
  int w = tid >> 6, l = tid & 63;
  int wr = w >> 2, wc = w & 3;            // wave -> 128x64 output sub-tile

  int rowOff = tid >> 2;
  int cbS = ((tid & 3) * 16) ^ (((tid >> 3) & 3) << 4);
  const char* xbB = (const char*)Xb;
  const char* wbB = (const char*)Wb;
  const char* src[4];
  src[0] = xbB + (size_t)(mBase +       rowOff) * (Ktot * 2) + cbS;  // A rows 0-127
  src[1] = xbB + (size_t)(mBase + 128 + rowOff) * (Ktot * 2) + cbS;  // A rows 128-255
  src[2] = wbB + (size_t)(nBase +       rowOff) * (Ktot * 2) + cbS;  // B rows 0-127
  src[3] = wbB + (size_t)(nBase + 128 + rowOff) * (Ktot * 2) + cbS;  // B rows 128-255
  int waveB = w * 1024;

  auto stage = [&](int bufn, int which, int tt) {
    lds16(src[which] + (size_t)tt * 64, smem + bufn * 32768 + which * 8192 + waveB);
  };

  // fragment read addressing (32x32x16): lane -> row cl=l&31, k-half hi=l>>5.
  // LDS byte = row*64 + ((ks*32 + hi*16) ^ xk), xk = ((cl>>1)&3)<<4 (matches
  // the write-side pre-swizzle key (row>>1)&3 since row mod 8 == cl mod 8).
  int cl = l & 31, hi = l >> 5;
  int xk = ((cl >> 1) & 3) << 4;
  int sl0 = (hi * 16) ^ xk;
  int sl1 = (32 + hi * 16) ^ xk;
  int aRd = (wr * 128 + cl) * 64;            // + ri*2048 + sl{0,1}
  int bRd = 16384 + (wc * 64 + cl) * 64;     // + ci*2048 + sl{0,1}

  f32x16 acc[4][2];
  {
    f32x16 z;
    #pragma unroll
    for (int q = 0; q < 16; ++q) z[q] = 0.0f;
    #pragma unroll
    for (int i = 0; i < 4; ++i)
      #pragma unroll
      for (int j = 0; j < 2; ++j) acc[i][j] = z;
  }

  bf16x8 aLo[2][2], aHi[2][2], bX[2][2], bY[2][2];

  // prologue: stage tiles 0,1; drain tile 0; prime tile-0 registers.
  #pragma unroll
  for (int q = 0; q < 4; ++q) stage(0, q, 0);
  #pragma unroll
  for (int q = 0; q < 4; ++q) stage(1, q, 1);
  asm volatile("s_waitcnt vmcnt(4)" ::: "memory");
  __syncthreads();
  #pragma unroll
  for (int ci = 0; ci < 2; ++ci) {
    bX[ci][0] = *reinterpret_cast<const bf16x8*>(smem + bRd + ci * 2048 + sl0);
    bX[ci][1] = *reinterpret_cast<const bf16x8*>(smem + bRd + ci * 2048 + sl1);
  }
  #pragma unroll
  for (int ri = 0; ri < 2; ++ri) {
    aLo[ri][0] = *reinterpret_cast<const bf16x8*>(smem + aRd + ri * 2048 + sl0);
    aLo[ri][1] = *reinterpret_cast<const bf16x8*>(smem + aRd + ri * 2048 + sl1);
  }

  auto tile_body = [&](int t, bf16x8 (&bCur)[2][2], bf16x8 (&bNxt)[2][2]) {
    const char* buf  = smem + (t & 3) * 32768;
    const char* bufN = smem + ((t + 1) & 3) * 32768;
    const bool pref = (t + 2 < NT);
    const int bn = (t + 2) & 3;

    if (pref) { stage(bn, 0, t + 2); stage(bn, 1, t + 2); }
    #pragma unroll
    for (int ri = 0; ri < 2; ++ri) {
      aHi[ri][0] = *reinterpret_cast<const bf16x8*>(buf + aRd + (2 + ri) * 2048 + sl0);
      aHi[ri][1] = *reinterpret_cast<const bf16x8*>(buf + aRd + (2 + ri) * 2048 + sl1);
    }
    __builtin_amdgcn_s_setprio(1);
    #pragma unroll
    for (int ri = 0; ri < 2; ++ri)
      #pragma unroll
      for (int ci = 0; ci < 2; ++ci)
        #pragma unroll
        for (int ks = 0; ks < 2; ++ks)
          acc[ri][ci] = __builtin_amdgcn_mfma_f32_32x32x16_bf16(aLo[ri][ks], bCur[ci][ks], acc[ri][ci], 0, 0, 0);
    __builtin_amdgcn_s_setprio(0);

    if (pref) asm volatile("s_waitcnt vmcnt(2)" ::: "memory");
    else      asm volatile("s_waitcnt vmcnt(0)" ::: "memory");
    __builtin_amdgcn_s_barrier();
    if (pref) { stage(bn, 2, t + 2); stage(bn, 3, t + 2); }

    if (t + 1 < NT) {
      #pragma unroll
      for (int ci = 0; ci < 2; ++ci) {
        bNxt[ci][0] = *reinterpret_cast<const bf16x8*>(bufN + bRd + ci * 2048 + sl0);
        bNxt[ci][1] = *reinterpret_cast<const bf16x8*>(bufN + bRd + ci * 2048 + sl1);
      }
      #pragma unroll
      for (int ri = 0; ri < 2; ++ri) {
        aLo[ri][0] = *reinterpret_cast<const bf16x8*>(bufN + aRd + ri * 2048 + sl0);
        aLo[ri][1] = *reinterpret_cast<const bf16x8*>(bufN + aRd + ri * 2048 + sl1);
      }
    }
    __builtin_amdgcn_s_setprio(1);
    #pragma unroll
    for (int ri = 0; ri < 2; ++ri)
      #pragma unroll
      for (int ci = 0; ci < 2; ++ci)
        #pragma unroll
        for (int ks = 0; ks < 2; ++ks)
          acc[2 + ri][ci] = __builtin_amdgcn_mfma_f32_32x32x16_bf16(aHi[ri][ks], bCur[ci][ks], acc[2 + ri][ci], 0, 0, 0);
    __builtin_amdgcn_s_setprio(0);
  };

  for (int t = 0; t < NT; t += 2) {
    tile_body(t,     bX, bY);
    tile_body(t + 1, bY, bX);
  }

  // epilogue: C/D col=lane&31, row=(reg&3)+8*(reg>>2)+4*hi
  #pragma unroll
  for (int ci = 0; ci < 2; ++ci) {
    int col = nBase + wc * 64 + ci * 32 + cl;
    float bb = bias[col];
    #pragma unroll
    for (int ri = 0; ri < 4; ++ri) {
      int rbase = mBase + wr * 128 + ri * 32 + hi * 4;
      #pragma unroll
      for (int r = 0; r < 16; ++r) {
        int row = rbase + (r & 3) + 8 * (r >> 2);
        out[(size_t)row * Ntot + col] = acc[ri][ci][r] + bb;
      }
    }
  }
}

extern "C" void kernel_launch(void* const* d_in, const int* in_sizes, int n_in,
                              void* d_out, int out_size, void* d_ws, size_t ws_size,
                              hipStream_t stream) {
  const float* x    = (const float*)d_in[0];
  const float* W    = (const float*)d_in[1];
  const float* bias = (const float*)d_in[2];
  const float* lA   = (const float*)d_in[3];
  const float* lB   = (const float*)d_in[4];
  const int*   mask = (const int*)d_in[5];
  float* out = (float*)d_out;

  ushort* xb  = (ushort*)d_ws;                      // [M][K]   bf16: 33.55 MB
  ushort* wb  = xb + (size_t)Mtot * Ktot;           // [N][K]   bf16:  8.39 MB
  ushort* abt = wb + (size_t)Ntot * Ktot;           // [K][128] bf16:  0.52 MB
  ushort* bst = abt + (size_t)Ktot * R2;            // [N][128] bf16:  0.52 MB

  k_prep<<<8192 + 8 + 8, 256, 0, stream>>>(x, xb, lA, lB, mask, abt, bst);
  k_weff_mfma<<<(Ntot / 128) * (Ktot / 128), 256, 0, stream>>>(bst, abt, W, wb);
  k_gemm256<<<(Mtot / 256) * (Ntot / 256), 512, 0, stream>>>(xb, wb, bias, out);
}